// Round 2
// baseline (864.228 us; speedup 1.0000x reference)
//
#include <hip/hip_runtime.h>
#include <math.h>

#define DNODE 128

__device__ __forceinline__ float wred(float v) {
#pragma unroll
  for (int m = 1; m < 64; m <<= 1) v += __shfl_xor(v, m, 64);
  return v;
}

// ---------------- row norms: inv[n] = 1 / max(||feat[n]||, 1e-12) ------------
__global__ void __launch_bounds__(256) norms_k(const float* __restrict__ feat,
                                               float* __restrict__ inv, int N) {
  int w = (blockIdx.x * blockDim.x + threadIdx.x) >> 6;
  int lane = threadIdx.x & 63;
  if (w >= N) return;
  float2 q = *reinterpret_cast<const float2*>(feat + (size_t)w * DNODE + lane * 2);
  float p = q.x * q.x + q.y * q.y;
  p = wred(p);
  if (lane == 0) {
    float nr = sqrtf(p);
    inv[w] = 1.0f / fmaxf(nr, 1e-12f);
  }
}

// ---------------- histogram of dst ------------------------------------------
__global__ void __launch_bounds__(256) hist_k(const int* __restrict__ dst,
                                              int* __restrict__ counts, int E) {
  int i = blockIdx.x * blockDim.x + threadIdx.x;
  int stride = gridDim.x * blockDim.x;
  for (; i < E; i += stride) atomicAdd(&counts[dst[i]], 1);
}

// ---------------- exclusive scan (single block, 4 elems/thread) --------------
__global__ void __launch_bounds__(1024) scan_k(const int* __restrict__ counts,
                                               int* __restrict__ offsets,
                                               int* __restrict__ cursor, int N) {
  __shared__ int wsum[16];
  __shared__ int carry_sh;
  int tid = threadIdx.x;
  if (tid == 0) { offsets[0] = 0; carry_sh = 0; }
  __syncthreads();
  for (int base = 0; base < N; base += 4096) {
    int idx = base + tid * 4;
    int v0 = (idx     < N) ? counts[idx]     : 0;
    int v1 = (idx + 1 < N) ? counts[idx + 1] : 0;
    int v2 = (idx + 2 < N) ? counts[idx + 2] : 0;
    int v3 = (idx + 3 < N) ? counts[idx + 3] : 0;
    int local = v0 + v1 + v2 + v3;
    int x = local;
#pragma unroll
    for (int d = 1; d < 64; d <<= 1) {
      int y = __shfl_up(x, d, 64);
      if ((tid & 63) >= d) x += y;
    }
    if ((tid & 63) == 63) wsum[tid >> 6] = x;
    __syncthreads();
    if (tid < 16) {
      int wv = wsum[tid];
#pragma unroll
      for (int d = 1; d < 16; d <<= 1) {
        int y = __shfl_up(wv, d, 64);
        if (tid >= d) wv += y;
      }
      wsum[tid] = wv;
    }
    __syncthreads();
    int carry = carry_sh;
    int waveoff = (tid >> 6) ? wsum[(tid >> 6) - 1] : 0;
    int incl = x + waveoff + carry;   // inclusive prefix incl. this thread's 4
    int excl = incl - local;
    if (idx     < N) { cursor[idx]     = excl;                offsets[idx + 1] = excl + v0; }
    if (idx + 1 < N) { cursor[idx + 1] = excl + v0;           offsets[idx + 2] = excl + v0 + v1; }
    if (idx + 2 < N) { cursor[idx + 2] = excl + v0 + v1;      offsets[idx + 3] = excl + v0 + v1 + v2; }
    if (idx + 3 < N) { cursor[idx + 3] = excl + v0 + v1 + v2; offsets[idx + 4] = excl + local; }
    __syncthreads();
    if (tid == 0) carry_sh = carry + wsum[15];
    __syncthreads();
  }
}

// ---------------- scatter src ids into dst-sorted order ----------------------
__global__ void __launch_bounds__(256) scatter_k(const int* __restrict__ src,
                                                 const int* __restrict__ dst,
                                                 int* __restrict__ cursor,
                                                 int* __restrict__ ssorted, int E) {
  int i = blockIdx.x * blockDim.x + threadIdx.x;
  int stride = gridDim.x * blockDim.x;
  for (; i < E; i += stride) {
    int p = atomicAdd(&cursor[dst[i]], 1);
    ssorted[p] = src[i];
  }
}

// ---------------- main: wave-per-node online-softmax aggregation -------------
__global__ void __launch_bounds__(256) agnn_main(
    const float* __restrict__ feat, const float* __restrict__ inv,
    const float* __restrict__ beta, const int* __restrict__ offsets,
    const int* __restrict__ ssorted, float* __restrict__ out, int N) {
  int w = (blockIdx.x * blockDim.x + threadIdx.x) >> 6;
  int lane = threadIdx.x & 63;
  if (w >= N) return;
  int beg = offsets[w], end = offsets[w + 1];
  float qb = inv[w] * beta[0];
  float2 q = *reinterpret_cast<const float2*>(feat + (size_t)w * DNODE + lane * 2);
  q.x *= qb; q.y *= qb;

  float m = -INFINITY, ssum = 0.0f;
  float ox = 0.0f, oy = 0.0f;

  for (int i = beg; i < end; i += 4) {
    int rem = end - i;
    int s0 = ssorted[i];
    int s1 = rem > 1 ? ssorted[i + 1] : s0;
    int s2 = rem > 2 ? ssorted[i + 2] : s0;
    int s3 = rem > 3 ? ssorted[i + 3] : s0;
    const float2 f0 = *reinterpret_cast<const float2*>(feat + (size_t)s0 * DNODE + lane * 2);
    const float2 f1 = *reinterpret_cast<const float2*>(feat + (size_t)s1 * DNODE + lane * 2);
    const float2 f2 = *reinterpret_cast<const float2*>(feat + (size_t)s2 * DNODE + lane * 2);
    const float2 f3 = *reinterpret_cast<const float2*>(feat + (size_t)s3 * DNODE + lane * 2);
    float i0 = inv[s0], i1 = inv[s1], i2 = inv[s2], i3 = inv[s3];
    float d0 = q.x * f0.x + q.y * f0.y;
    float d1 = q.x * f1.x + q.y * f1.y;
    float d2 = q.x * f2.x + q.y * f2.y;
    float d3 = q.x * f3.x + q.y * f3.y;
    d0 = wred(d0); d1 = wred(d1); d2 = wred(d2); d3 = wred(d3);
    float e0 = d0 * i0;
    float e1 = rem > 1 ? d1 * i1 : -INFINITY;
    float e2 = rem > 2 ? d2 * i2 : -INFINITY;
    float e3 = rem > 3 ? d3 * i3 : -INFINITY;
    float mx = fmaxf(fmaxf(e0, e1), fmaxf(e2, e3));
    float newm = fmaxf(m, mx);
    float fac = __expf(m - newm);         // exp(-inf)=0 on first iteration
    float p0 = __expf(e0 - newm);
    float p1 = __expf(e1 - newm);
    float p2 = __expf(e2 - newm);
    float p3 = __expf(e3 - newm);
    ox = ox * fac + p0 * f0.x + p1 * f1.x + p2 * f2.x + p3 * f3.x;
    oy = oy * fac + p0 * f0.y + p1 * f1.y + p2 * f2.y + p3 * f3.y;
    ssum = ssum * fac + p0 + p1 + p2 + p3;
    m = newm;
  }

  float r = (end > beg) ? 1.0f / ssum : 0.0f;   // degree-0 nodes -> zeros
  float2 res;
  res.x = ox * r;
  res.y = oy * r;
  *reinterpret_cast<float2*>(out + (size_t)w * DNODE + lane * 2) = res;
}

extern "C" void kernel_launch(void* const* d_in, const int* in_sizes, int n_in,
                              void* d_out, int out_size, void* d_ws, size_t ws_size,
                              hipStream_t stream) {
  const float* feat = (const float*)d_in[0];
  const float* beta = (const float*)d_in[1];
  const int* src = (const int*)d_in[2];
  const int* dst = (const int*)d_in[3];
  int N = in_sizes[0] / DNODE;
  int E = in_sizes[2];
  float* out = (float*)d_out;

  // workspace layout (ints): counts[N] | offsets[N+1] | cursor[N] | ssorted[E] | inv[N](f32)
  int* ws = (int*)d_ws;
  int* counts  = ws;
  int* offsets = ws + N;
  int* cursor  = ws + 2 * N + 1;
  int* ssorted = ws + 3 * N + 1;
  float* inv   = (float*)(ws + 3 * N + 1 + E);

  hipMemsetAsync(counts, 0, (size_t)N * sizeof(int), stream);
  hist_k<<<2048, 256, 0, stream>>>(dst, counts, E);
  scan_k<<<1, 1024, 0, stream>>>(counts, offsets, cursor, N);
  scatter_k<<<2048, 256, 0, stream>>>(src, dst, cursor, ssorted, E);
  norms_k<<<(N + 3) / 4, 256, 0, stream>>>(feat, inv, N);
  agnn_main<<<(N + 3) / 4, 256, 0, stream>>>(feat, inv, beta, offsets, ssorted, out, N);
}

// Round 4
// 452.337 us; speedup vs baseline: 1.9106x; 1.9106x over previous
//
#include <hip/hip_runtime.h>
#include <math.h>

#define DNODE 128
#define SHIFT 9                 // bucket = dst >> 9  (196 buckets for N=100K)
#define SRCB  23                // packed = (dst_low << 23) | src ; needs N <= 2^23
#define CAP4  28672             // LDS entries per bucket in nsort_k (112 KB)

__device__ __forceinline__ float wred(float v) {
#pragma unroll
  for (int m = 1; m < 64; m <<= 1) v += __shfl_xor(v, m, 64);
  return v;
}

// ---------------- row norms: inv[n] = 1 / max(||feat[n]||, 1e-12) ------------
__global__ void __launch_bounds__(256) norms_k(const float* __restrict__ feat,
                                               float* __restrict__ inv, int N) {
  int w = (blockIdx.x * blockDim.x + threadIdx.x) >> 6;
  int lane = threadIdx.x & 63;
  if (w >= N) return;
  float2 q = *reinterpret_cast<const float2*>(feat + (size_t)w * DNODE + lane * 2);
  float p = q.x * q.x + q.y * q.y;
  p = wred(p);
  if (lane == 0) {
    float nr = sqrtf(p);
    inv[w] = 1.0f / fmaxf(nr, 1e-12f);
  }
}

// ---------------- bucket histogram (dst >> SHIFT) ----------------------------
__global__ void __launch_bounds__(256) bhist_k(const int* __restrict__ dst,
                                               int* __restrict__ gbcount, int E) {
  __shared__ int h[256];
  int t = threadIdx.x;
  h[t] = 0;
  __syncthreads();
  for (long i = (long)blockIdx.x * 256 + t; i < E; i += (long)gridDim.x * 256)
    atomicAdd(&h[dst[i] >> SHIFT], 1);
  __syncthreads();
  if (h[t]) atomicAdd(&gbcount[t], h[t]);
}

// ---------------- scan bucket counts -> bases + cursors ----------------------
__global__ void __launch_bounds__(256) bscan_k(const int* __restrict__ gbcount,
                                               int* __restrict__ gbbase,
                                               int* __restrict__ gcursor,
                                               int* __restrict__ offsets,
                                               int NB, int N, int E) {
  __shared__ int sc[256];
  int t = threadIdx.x;
  int c = (t < NB) ? gbcount[t] : 0;
  sc[t] = c;
  __syncthreads();
#pragma unroll
  for (int d = 1; d < 256; d <<= 1) {
    int v = (t >= d) ? sc[t - d] : 0;
    __syncthreads();
    sc[t] += v;
    __syncthreads();
  }
  if (t < NB) {
    int base = sc[t] - c;       // exclusive
    gbbase[t] = base;
    gcursor[t] = base;
  }
  if (t == 0) {
    gbbase[NB] = E;
    offsets[N] = E;
  }
}

// ---------------- bin edges into bucket regions (packed u32) -----------------
#define T3 4096
__global__ void __launch_bounds__(256) bin_k(const int* __restrict__ src,
                                             const int* __restrict__ dst,
                                             int* __restrict__ gcursor,
                                             unsigned* __restrict__ binned, int E) {
  __shared__ int hist[256];
  __shared__ unsigned lcur[256];
  int t = threadIdx.x;
  long base = (long)blockIdx.x * T3;
  hist[t] = 0;
  __syncthreads();
  unsigned pk[16];
  int bk[16];
#pragma unroll
  for (int k = 0; k < 16; k++) {
    long i = base + t + k * 256;
    if (i < E) {
      int s = src[i], d = dst[i];
      int b = d >> SHIFT;
      pk[k] = ((unsigned)(d & ((1 << SHIFT) - 1)) << SRCB) | (unsigned)s;
      bk[k] = b;
      atomicAdd(&hist[b], 1);
    } else bk[k] = -1;
  }
  __syncthreads();
  int h = hist[t];
  lcur[t] = (h > 0) ? (unsigned)atomicAdd(&gcursor[t], h) : 0u;
  __syncthreads();
#pragma unroll
  for (int k = 0; k < 16; k++) {
    if (bk[k] >= 0) {
      unsigned pos = atomicAdd(&lcur[bk[k]], 1u);
      binned[pos] = pk[k];
    }
  }
}

// ---------------- per-bucket node sort (in place) + per-node offsets ---------
__global__ void __launch_bounds__(1024) nsort_k(unsigned* __restrict__ binned,
                                                const int* __restrict__ gbbase,
                                                int* __restrict__ offsets, int N) {
  __shared__ unsigned buf[CAP4];
  __shared__ int cnt[512];
  __shared__ int off[512];
  int b = blockIdx.x;
  int t = threadIdx.x;
  int beg = gbbase[b], end = gbbase[b + 1];
  int M = end - beg;
  int n0 = b << SHIFT;
  int nb_nodes = N - n0;
  if (nb_nodes > 512) nb_nodes = 512;
  if (t < 512) cnt[t] = 0;
  __syncthreads();
  for (int i = t; i < M; i += 1024) {
    unsigned v = binned[beg + i];
    if (i < CAP4) buf[i] = v;
    atomicAdd(&cnt[v >> SRCB], 1);
  }
  __syncthreads();
  if (t < 512) off[t] = cnt[t];
  __syncthreads();
#pragma unroll
  for (int d = 1; d < 512; d <<= 1) {
    int v = 0;
    if (t < 512 && t >= d) v = off[t - d];
    __syncthreads();
    if (t < 512) off[t] += v;
    __syncthreads();
  }
  // off = inclusive scan; exclusive = off - cnt
  if (t < nb_nodes) offsets[n0 + t] = beg + off[t] - cnt[t];
  if (t < 512) off[t] = beg + off[t] - cnt[t];   // global cursor
  __syncthreads();
  for (int i = t; i < M; i += 1024) {
    unsigned v = (i < CAP4) ? buf[i] : binned[beg + i];
    int nlow = v >> SRCB;
    int pos = atomicAdd(&off[nlow], 1);
    binned[pos] = v & ((1u << SRCB) - 1);        // now holds src only
  }
}

// ---------------- main: wave-per-node online-softmax aggregation -------------
__global__ void __launch_bounds__(256) agnn_main(
    const float* __restrict__ feat, const float* __restrict__ inv,
    const float* __restrict__ beta, const int* __restrict__ offsets,
    const unsigned* __restrict__ ssorted, float* __restrict__ out, int N) {
  int w = (blockIdx.x * blockDim.x + threadIdx.x) >> 6;
  int lane = threadIdx.x & 63;
  if (w >= N) return;
  int beg = offsets[w], end = offsets[w + 1];
  float qb = inv[w] * beta[0];
  float2 q = *reinterpret_cast<const float2*>(feat + (size_t)w * DNODE + lane * 2);
  q.x *= qb; q.y *= qb;

  float m = -INFINITY, ssum = 0.0f;
  float ox = 0.0f, oy = 0.0f;

  for (int i = beg; i < end; i += 8) {
    int rem = end - i;
    int s[8];
    int s0 = (int)ssorted[i];
#pragma unroll
    for (int k = 0; k < 8; k++) s[k] = (k < rem) ? (int)ssorted[i + k] : s0;
    float2 f[8];
#pragma unroll
    for (int k = 0; k < 8; k++)
      f[k] = *reinterpret_cast<const float2*>(feat + (size_t)s[k] * DNODE + lane * 2);
    float iv[8];
#pragma unroll
    for (int k = 0; k < 8; k++) iv[k] = inv[s[k]];
    float e[8];
#pragma unroll
    for (int k = 0; k < 8; k++) {
      float d = q.x * f[k].x + q.y * f[k].y;
      d = wred(d);
      e[k] = (k < rem) ? d * iv[k] : -INFINITY;
    }
    float mx = e[0];
#pragma unroll
    for (int k = 1; k < 8; k++) mx = fmaxf(mx, e[k]);
    float newm = fmaxf(m, mx);
    float fac = __expf(m - newm);         // exp(-inf)=0 on first iteration
    float p[8];
#pragma unroll
    for (int k = 0; k < 8; k++) p[k] = __expf(e[k] - newm);
    float ax = 0.0f, ay = 0.0f, aps = 0.0f;
#pragma unroll
    for (int k = 0; k < 8; k++) {
      ax += p[k] * f[k].x;
      ay += p[k] * f[k].y;
      aps += p[k];
    }
    ox = ox * fac + ax;
    oy = oy * fac + ay;
    ssum = ssum * fac + aps;
    m = newm;
  }

  float r = (end > beg) ? 1.0f / ssum : 0.0f;   // degree-0 nodes -> zeros
  float2 res;
  res.x = ox * r;
  res.y = oy * r;
  *reinterpret_cast<float2*>(out + (size_t)w * DNODE + lane * 2) = res;
}

extern "C" void kernel_launch(void* const* d_in, const int* in_sizes, int n_in,
                              void* d_out, int out_size, void* d_ws, size_t ws_size,
                              hipStream_t stream) {
  const float* feat = (const float*)d_in[0];
  const float* beta = (const float*)d_in[1];
  const int* src = (const int*)d_in[2];
  const int* dst = (const int*)d_in[3];
  int N = in_sizes[0] / DNODE;
  int E = in_sizes[2];
  float* out = (float*)d_out;
  int NB = (N + (1 << SHIFT) - 1) >> SHIFT;

  // workspace (ints): gbcount[256] | gcursor[256] | gbbase[257] | offsets[N+1]
  //                   | binned[E] (packed -> becomes src-sorted) | inv[N] (f32)
  int* ws = (int*)d_ws;
  int* gbcount = ws;
  int* gcursor = ws + 256;
  int* gbbase  = ws + 512;
  int* offsets = ws + 769;
  unsigned* binned = (unsigned*)(ws + 769 + N + 1);
  float* inv = (float*)(ws + 770 + N + E);

  hipMemsetAsync(gbcount, 0, 256 * sizeof(int), stream);
  bhist_k<<<1024, 256, 0, stream>>>(dst, gbcount, E);
  bscan_k<<<1, 256, 0, stream>>>(gbcount, gbbase, gcursor, offsets, NB, N, E);
  bin_k<<<(E + T3 - 1) / T3, 256, 0, stream>>>(src, dst, gcursor, binned, E);
  nsort_k<<<NB, 1024, 0, stream>>>(binned, gbbase, offsets, N);
  norms_k<<<(N + 3) / 4, 256, 0, stream>>>(feat, inv, N);
  agnn_main<<<(N + 3) / 4, 256, 0, stream>>>(feat, inv, beta, offsets, binned, out, N);
}

// Round 6
// 377.438 us; speedup vs baseline: 2.2897x; 1.1984x over previous
//
#include <hip/hip_runtime.h>
#include <hip/hip_fp16.h>
#include <math.h>

#define DNODE 128
#define SHIFT 9                 // bucket = dst >> 9  (196 buckets for N=100K)
#define SRCB  23                // packed = (dst_low << 23) | src ; needs N <= 2^23
#define CAP4  28672             // LDS entries per bucket in nsort_k (112 KB)

__device__ __forceinline__ float wred(float v) {
#pragma unroll
  for (int m = 1; m < 64; m <<= 1) v += __shfl_xor(v, m, 64);
  return v;
}

// -------- row norms + optional fp16 conversion -------------------------------
template <int CONV>
__global__ void __launch_bounds__(256) norms_k(const float* __restrict__ feat,
                                               float* __restrict__ inv,
                                               __half* __restrict__ hfeat, int N) {
  int w = (blockIdx.x * blockDim.x + threadIdx.x) >> 6;
  int lane = threadIdx.x & 63;
  if (w >= N) return;
  float2 q = *reinterpret_cast<const float2*>(feat + (size_t)w * DNODE + lane * 2);
  if (CONV) {
    __half2 h = __float22half2_rn(q);
    *reinterpret_cast<__half2*>(hfeat + (size_t)w * DNODE + lane * 2) = h;
  }
  float p = q.x * q.x + q.y * q.y;
  p = wred(p);
  if (lane == 0) inv[w] = 1.0f / fmaxf(sqrtf(p), 1e-12f);
}

// ---------------- bucket histogram (dst >> SHIFT) ----------------------------
__global__ void __launch_bounds__(256) bhist_k(const int* __restrict__ dst,
                                               int* __restrict__ gbcount, int E) {
  __shared__ int h[256];
  int t = threadIdx.x;
  h[t] = 0;
  __syncthreads();
  for (long i = (long)blockIdx.x * 256 + t; i < E; i += (long)gridDim.x * 256)
    atomicAdd(&h[dst[i] >> SHIFT], 1);
  __syncthreads();
  if (h[t]) atomicAdd(&gbcount[t], h[t]);
}

// ---------------- scan bucket counts -> bases + cursors ----------------------
__global__ void __launch_bounds__(256) bscan_k(const int* __restrict__ gbcount,
                                               int* __restrict__ gbbase,
                                               int* __restrict__ gcursor,
                                               int* __restrict__ offsets,
                                               int NB, int N, int E) {
  __shared__ int sc[256];
  int t = threadIdx.x;
  int c = (t < NB) ? gbcount[t] : 0;
  sc[t] = c;
  __syncthreads();
#pragma unroll
  for (int d = 1; d < 256; d <<= 1) {
    int v = (t >= d) ? sc[t - d] : 0;
    __syncthreads();
    sc[t] += v;
    __syncthreads();
  }
  if (t < NB) {
    int base = sc[t] - c;       // exclusive
    gbbase[t] = base;
    gcursor[t] = base;
  }
  if (t == 0) {
    gbbase[NB] = E;
    offsets[N] = E;
  }
}

// ---------------- bin edges into bucket regions (packed u32) -----------------
#define T3 4096
__global__ void __launch_bounds__(256) bin_k(const int* __restrict__ src,
                                             const int* __restrict__ dst,
                                             int* __restrict__ gcursor,
                                             unsigned* __restrict__ binned, int E) {
  __shared__ int hist[256];
  __shared__ unsigned lcur[256];
  int t = threadIdx.x;
  long base = (long)blockIdx.x * T3;
  hist[t] = 0;
  __syncthreads();
  unsigned pk[16];
  int bk[16];
#pragma unroll
  for (int k = 0; k < 16; k++) {
    long i = base + t + k * 256;
    if (i < E) {
      int s = src[i], d = dst[i];
      int b = d >> SHIFT;
      pk[k] = ((unsigned)(d & ((1 << SHIFT) - 1)) << SRCB) | (unsigned)s;
      bk[k] = b;
      atomicAdd(&hist[b], 1);
    } else bk[k] = -1;
  }
  __syncthreads();
  int h = hist[t];
  lcur[t] = (h > 0) ? (unsigned)atomicAdd(&gcursor[t], h) : 0u;
  __syncthreads();
#pragma unroll
  for (int k = 0; k < 16; k++) {
    if (bk[k] >= 0) {
      unsigned pos = atomicAdd(&lcur[bk[k]], 1u);
      binned[pos] = pk[k];
    }
  }
}

// ---------------- per-bucket node sort (in place) + per-node offsets ---------
__global__ void __launch_bounds__(1024) nsort_k(unsigned* __restrict__ binned,
                                                const int* __restrict__ gbbase,
                                                int* __restrict__ offsets, int N) {
  __shared__ unsigned buf[CAP4];
  __shared__ int cnt[512];
  __shared__ int off[512];
  int b = blockIdx.x;
  int t = threadIdx.x;
  int beg = gbbase[b], end = gbbase[b + 1];
  int M = end - beg;
  int n0 = b << SHIFT;
  int nb_nodes = N - n0;
  if (nb_nodes > 512) nb_nodes = 512;
  if (t < 512) cnt[t] = 0;
  __syncthreads();
  for (int i = t; i < M; i += 1024) {
    unsigned v = binned[beg + i];
    if (i < CAP4) buf[i] = v;
    atomicAdd(&cnt[v >> SRCB], 1);
  }
  __syncthreads();
  if (t < 512) off[t] = cnt[t];
  __syncthreads();
#pragma unroll
  for (int d = 1; d < 512; d <<= 1) {
    int v = 0;
    if (t < 512 && t >= d) v = off[t - d];
    __syncthreads();
    if (t < 512) off[t] += v;
    __syncthreads();
  }
  // off = inclusive scan; exclusive = off - cnt
  if (t < nb_nodes) offsets[n0 + t] = beg + off[t] - cnt[t];
  if (t < 512) off[t] = beg + off[t] - cnt[t];   // global cursor
  __syncthreads();
  for (int i = t; i < M; i += 1024) {
    unsigned v = (i < CAP4) ? buf[i] : binned[beg + i];
    int nlow = v >> SRCB;
    int pos = atomicAdd(&off[nlow], 1);
    binned[pos] = v & ((1u << SRCB) - 1);        // now holds src only
  }
}

// -------- main: pair-gather + multi-value butterfly online softmax -----------
// Lanes 0-31 own even edges of each 8-block, lanes 32-63 odd edges. Each lane
// holds components 4*(lane&31)..+3 of its edge's row. Dots reduce via a
// tournament: after mask-16 and mask-8 merges, 8-lane group g = lane>>3 holds
// edge 2*(g&3) (g<4) / 2*(g&3)+1 (g>=4); one exp covers all 8 edges.
template <int HALFMODE>
__global__ void __launch_bounds__(256) agnn_main(
    const float* __restrict__ feat, const __half* __restrict__ hfeat,
    const float* __restrict__ inv, const float* __restrict__ beta,
    const int* __restrict__ offsets, const unsigned* __restrict__ ssorted,
    float* __restrict__ out, int N) {
  int w = (blockIdx.x * blockDim.x + threadIdx.x) >> 6;
  int lane = threadIdx.x & 63;
  if (w >= N) return;
  int beg = offsets[w], end = offsets[w + 1];
  int l5 = lane & 32;
  int l31 = lane & 31;
  float qb = inv[w] * beta[0];
  float4 q = *reinterpret_cast<const float4*>(feat + (size_t)w * DNODE + l31 * 4);
  q.x *= qb; q.y *= qb; q.z *= qb; q.w *= qb;

  float m = -INFINITY, ssum = 0.0f;
  float a0 = 0.f, a1 = 0.f, a2 = 0.f, a3 = 0.f;
  bool b4 = (lane & 16) != 0;
  bool b3 = (lane & 8) != 0;

  for (int i = beg; i < end; i += 8) {
    int rem = end - i;
    int sv[8];
#pragma unroll
    for (int k = 0; k < 8; k++) sv[k] = (int)ssorted[i + (k < rem ? k : 0)];

    float pr[4], fc0[4], fc1[4], fc2[4], fc3[4];
#pragma unroll
    for (int j = 0; j < 4; j++) {
      int sp = l5 ? sv[2 * j + 1] : sv[2 * j];
      float c0, c1, c2, c3;
      if (HALFMODE) {
        uint2 hv = *reinterpret_cast<const uint2*>(hfeat + (size_t)sp * DNODE + l31 * 4);
        __half2 h0 = *reinterpret_cast<__half2*>(&hv.x);
        __half2 h1 = *reinterpret_cast<__half2*>(&hv.y);
        float2 f0 = __half22float2(h0), f1 = __half22float2(h1);
        c0 = f0.x; c1 = f0.y; c2 = f1.x; c3 = f1.y;
      } else {
        float4 ff = *reinterpret_cast<const float4*>(feat + (size_t)sp * DNODE + l31 * 4);
        c0 = ff.x; c1 = ff.y; c2 = ff.z; c3 = ff.w;
      }
      float iv = inv[sp];
      float d = (q.x * c0 + q.y * c1 + q.z * c2 + q.w * c3) * iv;
      int eidx = 2 * j + (l5 ? 1 : 0);
      if (eidx >= rem) d = -INFINITY;
      pr[j] = d; fc0[j] = c0; fc1[j] = c1; fc2[j] = c2; fc3[j] = c3;
    }

    // multi-value reduce within each 32-lane half (each half holds full rows)
    // mask 16: b4=0 lanes accumulate pr[0] pairs, b4=1 lanes pr[2] pairs (r0);
    //          likewise pr[1]/pr[3] into r1.
    float r0 = (b4 ? pr[2] : pr[0]) + __shfl_xor(b4 ? pr[0] : pr[2], 16);
    float r1 = (b4 ? pr[3] : pr[1]) + __shfl_xor(b4 ? pr[1] : pr[3], 16);
    // mask 8: b3=0 lanes keep r0 (recv partner's r0), b3=1 keep r1.
    float c = (b3 ? r1 : r0) + __shfl_xor(b3 ? r0 : r1, 8);
    c += __shfl_xor(c, 4);
    c += __shfl_xor(c, 2);
    c += __shfl_xor(c, 1);
    // group g=lane>>3: g<4 -> edge 2*(g&3); g>=4 -> edge 2*(g&3)+1

    float mx = c;
    mx = fmaxf(mx, __shfl_xor(mx, 8));
    mx = fmaxf(mx, __shfl_xor(mx, 16));
    mx = fmaxf(mx, __shfl_xor(mx, 32));
    float newm = fmaxf(m, mx);
    float fac = __expf(m - newm);          // exp(-inf)=0 first round
    float p = __expf(c - newm);            // one exp covers all 8 edges
    float ps = p;
    ps += __shfl_xor(ps, 8);
    ps += __shfl_xor(ps, 16);
    ps += __shfl_xor(ps, 32);
    ssum = ssum * fac + ps;
    a0 *= fac; a1 *= fac; a2 *= fac; a3 *= fac;
#pragma unroll
    for (int j = 0; j < 4; j++) {
      // edge 2j lives in group j (lanes<32), edge 2j+1 in group j+4 (lanes>=32)
      float pb = __shfl(p, j * 8 + l5, 64);
      a0 = fmaf(pb, fc0[j], a0);
      a1 = fmaf(pb, fc1[j], a1);
      a2 = fmaf(pb, fc2[j], a2);
      a3 = fmaf(pb, fc3[j], a3);
    }
    m = newm;
  }

  a0 += __shfl_xor(a0, 32);
  a1 += __shfl_xor(a1, 32);
  a2 += __shfl_xor(a2, 32);
  a3 += __shfl_xor(a3, 32);
  float r = (end > beg) ? 1.0f / ssum : 0.0f;
  if (lane < 32) {
    float4 res = make_float4(a0 * r, a1 * r, a2 * r, a3 * r);
    *reinterpret_cast<float4*>(out + (size_t)w * DNODE + l31 * 4) = res;
  }
}

extern "C" void kernel_launch(void* const* d_in, const int* in_sizes, int n_in,
                              void* d_out, int out_size, void* d_ws, size_t ws_size,
                              hipStream_t stream) {
  const float* feat = (const float*)d_in[0];
  const float* beta = (const float*)d_in[1];
  const int* src = (const int*)d_in[2];
  const int* dst = (const int*)d_in[3];
  int N = in_sizes[0] / DNODE;
  int E = in_sizes[2];
  float* out = (float*)d_out;
  int NB = (N + (1 << SHIFT) - 1) >> SHIFT;

  // HALF layout: hfeat[N*128 fp16] | gbcount[256] gcursor[256] gbbase[257] |
  //              offsets[N+1] | binned[E] | inv[N]
  size_t intWords = 769ull + (size_t)N + 1 + (size_t)E + (size_t)N;
  size_t needH = (size_t)N * 256 + 4ull * intWords;
  bool halfmode = ws_size >= needH;

  char* wsb = (char*)d_ws;
  __half* hfeat = (__half*)wsb;
  int* ib = halfmode ? (int*)(wsb + (size_t)N * 256) : (int*)wsb;
  int* gbcount = ib;
  int* gcursor = ib + 256;
  int* gbbase  = ib + 512;
  int* offsets = ib + 769;
  unsigned* binned = (unsigned*)(ib + 769 + N + 1);
  float* inv = (float*)(ib + 770 + N + E);

  hipMemsetAsync(gbcount, 0, 256 * sizeof(int), stream);
  bhist_k<<<1024, 256, 0, stream>>>(dst, gbcount, E);
  bscan_k<<<1, 256, 0, stream>>>(gbcount, gbbase, gcursor, offsets, NB, N, E);
  bin_k<<<(E + T3 - 1) / T3, 256, 0, stream>>>(src, dst, gcursor, binned, E);
  nsort_k<<<NB, 1024, 0, stream>>>(binned, gbbase, offsets, N);
  if (halfmode) {
    norms_k<1><<<(N + 3) / 4, 256, 0, stream>>>(feat, inv, hfeat, N);
    agnn_main<1><<<(N + 3) / 4, 256, 0, stream>>>(feat, hfeat, inv, beta, offsets, binned, out, N);
  } else {
    norms_k<0><<<(N + 3) / 4, 256, 0, stream>>>(feat, inv, nullptr, N);
    agnn_main<0><<<(N + 3) / 4, 256, 0, stream>>>(feat, nullptr, inv, beta, offsets, binned, out, N);
  }
}

// Round 8
// 329.179 us; speedup vs baseline: 2.6254x; 1.1466x over previous
//
#include <hip/hip_runtime.h>
#include <hip/hip_fp16.h>
#include <math.h>

#define DNODE 128
#define SHIFT 9                 // bucket = dst >> 9  (196 buckets for N=100K)
#define SRCB  23                // packed = (dst_low << 23) | src ; needs N <= 2^23
#define CAP4  28672             // LDS entries per bucket in nsort_k (112 KB)

__device__ __forceinline__ float wred(float v) {
#pragma unroll
  for (int m = 1; m < 64; m <<= 1) v += __shfl_xor(v, m, 64);
  return v;
}

// -------- row norms + optional fp16 conversion -------------------------------
template <int CONV>
__global__ void __launch_bounds__(256) norms_k(const float* __restrict__ feat,
                                               float* __restrict__ inv,
                                               __half* __restrict__ hfeat, int N) {
  int w = (blockIdx.x * blockDim.x + threadIdx.x) >> 6;
  int lane = threadIdx.x & 63;
  if (w >= N) return;
  float2 q = *reinterpret_cast<const float2*>(feat + (size_t)w * DNODE + lane * 2);
  if (CONV) {
    __half2 h = __float22half2_rn(q);
    *reinterpret_cast<__half2*>(hfeat + (size_t)w * DNODE + lane * 2) = h;
  }
  float p = q.x * q.x + q.y * q.y;
  p = wred(p);
  if (lane == 0) inv[w] = 1.0f / fmaxf(sqrtf(p), 1e-12f);
}

// ---------------- bucket histogram (dst >> SHIFT) ----------------------------
__global__ void __launch_bounds__(256) bhist_k(const int* __restrict__ dst,
                                               int* __restrict__ gbcount, int E) {
  __shared__ int h[256];
  int t = threadIdx.x;
  h[t] = 0;
  __syncthreads();
  for (long i = (long)blockIdx.x * 256 + t; i < E; i += (long)gridDim.x * 256)
    atomicAdd(&h[dst[i] >> SHIFT], 1);
  __syncthreads();
  if (h[t]) atomicAdd(&gbcount[t], h[t]);
}

// ---------------- scan bucket counts -> bases + cursors ----------------------
__global__ void __launch_bounds__(256) bscan_k(const int* __restrict__ gbcount,
                                               int* __restrict__ gbbase,
                                               int* __restrict__ gcursor,
                                               int* __restrict__ offsets,
                                               int NB, int N, int E) {
  __shared__ int sc[256];
  int t = threadIdx.x;
  int c = (t < NB) ? gbcount[t] : 0;
  sc[t] = c;
  __syncthreads();
#pragma unroll
  for (int d = 1; d < 256; d <<= 1) {
    int v = (t >= d) ? sc[t - d] : 0;
    __syncthreads();
    sc[t] += v;
    __syncthreads();
  }
  if (t < NB) {
    int base = sc[t] - c;       // exclusive
    gbbase[t] = base;
    gcursor[t] = base;
  }
  if (t == 0) {
    gbbase[NB] = E;
    offsets[N] = E;
  }
}

// ---------------- bin edges into bucket regions (packed u32) -----------------
#define T3 4096
__global__ void __launch_bounds__(256) bin_k(const int* __restrict__ src,
                                             const int* __restrict__ dst,
                                             int* __restrict__ gcursor,
                                             unsigned* __restrict__ binned, int E) {
  __shared__ int hist[256];
  __shared__ unsigned lcur[256];
  int t = threadIdx.x;
  long base = (long)blockIdx.x * T3;
  hist[t] = 0;
  __syncthreads();
  unsigned pk[16];
  int bk[16];
#pragma unroll
  for (int k = 0; k < 16; k++) {
    long i = base + t + k * 256;
    if (i < E) {
      int s = src[i], d = dst[i];
      int b = d >> SHIFT;
      pk[k] = ((unsigned)(d & ((1 << SHIFT) - 1)) << SRCB) | (unsigned)s;
      bk[k] = b;
      atomicAdd(&hist[b], 1);
    } else bk[k] = -1;
  }
  __syncthreads();
  int h = hist[t];
  lcur[t] = (h > 0) ? (unsigned)atomicAdd(&gcursor[t], h) : 0u;
  __syncthreads();
#pragma unroll
  for (int k = 0; k < 16; k++) {
    if (bk[k] >= 0) {
      unsigned pos = atomicAdd(&lcur[bk[k]], 1u);
      binned[pos] = pk[k];
    }
  }
}

// ---------------- per-bucket node sort (in place) + per-node offsets ---------
__global__ void __launch_bounds__(1024) nsort_k(unsigned* __restrict__ binned,
                                                const int* __restrict__ gbbase,
                                                int* __restrict__ offsets, int N) {
  __shared__ unsigned buf[CAP4];
  __shared__ int cnt[512];
  __shared__ int off[512];
  int b = blockIdx.x;
  int t = threadIdx.x;
  int beg = gbbase[b], end = gbbase[b + 1];
  int M = end - beg;
  int n0 = b << SHIFT;
  int nb_nodes = N - n0;
  if (nb_nodes > 512) nb_nodes = 512;
  if (t < 512) cnt[t] = 0;
  __syncthreads();
  for (int i = t; i < M; i += 1024) {
    unsigned v = binned[beg + i];
    if (i < CAP4) buf[i] = v;
    atomicAdd(&cnt[v >> SRCB], 1);
  }
  __syncthreads();
  if (t < 512) off[t] = cnt[t];
  __syncthreads();
#pragma unroll
  for (int d = 1; d < 512; d <<= 1) {
    int v = 0;
    if (t < 512 && t >= d) v = off[t - d];
    __syncthreads();
    if (t < 512) off[t] += v;
    __syncthreads();
  }
  // off = inclusive scan; exclusive = off - cnt
  if (t < nb_nodes) offsets[n0 + t] = beg + off[t] - cnt[t];
  if (t < 512) off[t] = beg + off[t] - cnt[t];   // global cursor
  __syncthreads();
  for (int i = t; i < M; i += 1024) {
    unsigned v = (i < CAP4) ? buf[i] : binned[beg + i];
    int nlow = v >> SRCB;
    int pos = atomicAdd(&off[nlow], 1);
    binned[pos] = v & ((1u << SRCB) - 1);        // now holds src only
  }
}

// -------- main: 16-lane-per-edge, fixed-max softmax (|e| <= |beta|) ----------
// Wave = 4 edge-groups of 16 lanes. Lane owns components 8*(lane&15)..+7.
// Dot reduce: 4 shfl_xor (masks 8,4,2,1) inside the group; afterwards every
// lane of the group holds the full score -> zero broadcasts for accumulation.
// Scores are bounded: e = beta*cos in [-|beta|,|beta|], so exp(e-|beta|) is
// always in [e^-2,~1] and no online max/rescale is needed (constant max
// cancels in the final normalization).
template <int HALFMODE>
__global__ void __launch_bounds__(256) agnn_main(
    const float* __restrict__ feat, const __half* __restrict__ hfeat,
    const float* __restrict__ inv, const float* __restrict__ beta,
    const int* __restrict__ offsets, const unsigned* __restrict__ ssorted,
    float* __restrict__ out, int N) {
  int w = (blockIdx.x * blockDim.x + threadIdx.x) >> 6;
  int lane = threadIdx.x & 63;
  if (w >= N) return;
  int beg = offsets[w], end = offsets[w + 1];
  int g = lane >> 4;            // edge group 0..3
  int l16 = lane & 15;          // component-slice owner
  float bt = beta[0];
  float mfix = fabsf(bt);
  float qb = inv[w] * bt;
  float qv[8];
  {
    float4 qa = *reinterpret_cast<const float4*>(feat + (size_t)w * DNODE + l16 * 8);
    float4 qc = *reinterpret_cast<const float4*>(feat + (size_t)w * DNODE + l16 * 8 + 4);
    qv[0] = qa.x * qb; qv[1] = qa.y * qb; qv[2] = qa.z * qb; qv[3] = qa.w * qb;
    qv[4] = qc.x * qb; qv[5] = qc.y * qb; qv[6] = qc.z * qb; qv[7] = qc.w * qb;
  }

  float ssum = 0.0f;
  float a[8];
#pragma unroll
  for (int k = 0; k < 8; k++) a[k] = 0.f;

  for (int i = beg; i < end; i += 8) {
    int rem = end - i;
    int eA = g, eB = g + 4;
    int spA = (int)ssorted[i + ((eA < rem) ? eA : 0)];
    int spB = (int)ssorted[i + ((eB < rem) ? eB : 0)];
    float fA[8], fB[8];
    if (HALFMODE) {
      uint4 hv = *reinterpret_cast<const uint4*>(hfeat + (size_t)spA * DNODE + l16 * 8);
      float2 u0 = __half22float2(*reinterpret_cast<__half2*>(&hv.x));
      float2 u1 = __half22float2(*reinterpret_cast<__half2*>(&hv.y));
      float2 u2 = __half22float2(*reinterpret_cast<__half2*>(&hv.z));
      float2 u3 = __half22float2(*reinterpret_cast<__half2*>(&hv.w));
      fA[0] = u0.x; fA[1] = u0.y; fA[2] = u1.x; fA[3] = u1.y;
      fA[4] = u2.x; fA[5] = u2.y; fA[6] = u3.x; fA[7] = u3.y;
      uint4 hw = *reinterpret_cast<const uint4*>(hfeat + (size_t)spB * DNODE + l16 * 8);
      float2 v0 = __half22float2(*reinterpret_cast<__half2*>(&hw.x));
      float2 v1 = __half22float2(*reinterpret_cast<__half2*>(&hw.y));
      float2 v2 = __half22float2(*reinterpret_cast<__half2*>(&hw.z));
      float2 v3 = __half22float2(*reinterpret_cast<__half2*>(&hw.w));
      fB[0] = v0.x; fB[1] = v0.y; fB[2] = v1.x; fB[3] = v1.y;
      fB[4] = v2.x; fB[5] = v2.y; fB[6] = v3.x; fB[7] = v3.y;
    } else {
      float4 x0 = *reinterpret_cast<const float4*>(feat + (size_t)spA * DNODE + l16 * 8);
      float4 x1 = *reinterpret_cast<const float4*>(feat + (size_t)spA * DNODE + l16 * 8 + 4);
      fA[0] = x0.x; fA[1] = x0.y; fA[2] = x0.z; fA[3] = x0.w;
      fA[4] = x1.x; fA[5] = x1.y; fA[6] = x1.z; fA[7] = x1.w;
      float4 y0 = *reinterpret_cast<const float4*>(feat + (size_t)spB * DNODE + l16 * 8);
      float4 y1 = *reinterpret_cast<const float4*>(feat + (size_t)spB * DNODE + l16 * 8 + 4);
      fB[0] = y0.x; fB[1] = y0.y; fB[2] = y0.z; fB[3] = y0.w;
      fB[4] = y1.x; fB[5] = y1.y; fB[6] = y1.z; fB[7] = y1.w;
    }
    float ivA = inv[spA], ivB = inv[spB];
    float dA = qv[0] * fA[0], dB = qv[0] * fB[0];
#pragma unroll
    for (int k = 1; k < 8; k++) {
      dA = fmaf(qv[k], fA[k], dA);
      dB = fmaf(qv[k], fB[k], dB);
    }
    // two independent 4-step chains (masks 8,4,2,1 stay inside 16-lane group)
    dA += __shfl_xor(dA, 8);  dB += __shfl_xor(dB, 8);
    dA += __shfl_xor(dA, 4);  dB += __shfl_xor(dB, 4);
    dA += __shfl_xor(dA, 2);  dB += __shfl_xor(dB, 2);
    dA += __shfl_xor(dA, 1);  dB += __shfl_xor(dB, 1);
    float pA = (eA < rem) ? __expf(dA * ivA - mfix) : 0.f;
    float pB = (eB < rem) ? __expf(dB * ivB - mfix) : 0.f;
    ssum += pA + pB;
#pragma unroll
    for (int k = 0; k < 8; k++) a[k] = fmaf(pA, fA[k], fmaf(pB, fB[k], a[k]));
  }

  // combine the 4 groups (masks 16,32), once per node
#pragma unroll
  for (int k = 0; k < 8; k++) {
    a[k] += __shfl_xor(a[k], 16);
    a[k] += __shfl_xor(a[k], 32);
  }
  ssum += __shfl_xor(ssum, 16);
  ssum += __shfl_xor(ssum, 32);
  float r = (end > beg) ? 1.0f / ssum : 0.0f;
  if (lane < 16) {
    float4 r0 = make_float4(a[0] * r, a[1] * r, a[2] * r, a[3] * r);
    float4 r1 = make_float4(a[4] * r, a[5] * r, a[6] * r, a[7] * r);
    *reinterpret_cast<float4*>(out + (size_t)w * DNODE + l16 * 8) = r0;
    *reinterpret_cast<float4*>(out + (size_t)w * DNODE + l16 * 8 + 4) = r1;
  }
}

extern "C" void kernel_launch(void* const* d_in, const int* in_sizes, int n_in,
                              void* d_out, int out_size, void* d_ws, size_t ws_size,
                              hipStream_t stream) {
  const float* feat = (const float*)d_in[0];
  const float* beta = (const float*)d_in[1];
  const int* src = (const int*)d_in[2];
  const int* dst = (const int*)d_in[3];
  int N = in_sizes[0] / DNODE;
  int E = in_sizes[2];
  float* out = (float*)d_out;
  int NB = (N + (1 << SHIFT) - 1) >> SHIFT;

  // HALF layout: hfeat[N*128 fp16] | gbcount[256] gcursor[256] gbbase[257] |
  //              offsets[N+1] | binned[E] | inv[N]
  size_t intWords = 769ull + (size_t)N + 1 + (size_t)E + (size_t)N;
  size_t needH = (size_t)N * 256 + 4ull * intWords;
  bool halfmode = ws_size >= needH;

  char* wsb = (char*)d_ws;
  __half* hfeat = (__half*)wsb;
  int* ib = halfmode ? (int*)(wsb + (size_t)N * 256) : (int*)wsb;
  int* gbcount = ib;
  int* gcursor = ib + 256;
  int* gbbase  = ib + 512;
  int* offsets = ib + 769;
  unsigned* binned = (unsigned*)(ib + 769 + N + 1);
  float* inv = (float*)(ib + 770 + N + E);

  hipMemsetAsync(gbcount, 0, 256 * sizeof(int), stream);
  bhist_k<<<1024, 256, 0, stream>>>(dst, gbcount, E);
  bscan_k<<<1, 256, 0, stream>>>(gbcount, gbbase, gcursor, offsets, NB, N, E);
  bin_k<<<(E + T3 - 1) / T3, 256, 0, stream>>>(src, dst, gcursor, binned, E);
  nsort_k<<<NB, 1024, 0, stream>>>(binned, gbbase, offsets, N);
  if (halfmode) {
    norms_k<1><<<(N + 3) / 4, 256, 0, stream>>>(feat, inv, hfeat, N);
    agnn_main<1><<<(N + 3) / 4, 256, 0, stream>>>(feat, hfeat, inv, beta, offsets, binned, out, N);
  } else {
    norms_k<0><<<(N + 3) / 4, 256, 0, stream>>>(feat, inv, nullptr, N);
    agnn_main<0><<<(N + 3) / 4, 256, 0, stream>>>(feat, nullptr, inv, beta, offsets, binned, out, N);
  }
}